// Round 8
// baseline (195.813 us; speedup 1.0000x reference)
//
#include <hip/hip_runtime.h>
#include <stdint.h>

#define N_SEQ 4096

typedef float f32x4 __attribute__((ext_vector_type(4)));
typedef float f32x2 __attribute__((ext_vector_type(2)));
typedef unsigned short u16x8 __attribute__((ext_vector_type(8)));
typedef unsigned short u16x4 __attribute__((ext_vector_type(4)));
typedef unsigned int u32x2 __attribute__((ext_vector_type(2)));
typedef __bf16 bf16x8 __attribute__((ext_vector_type(8)));

static __device__ __forceinline__ float bf2f(unsigned short u) {
    unsigned v = ((unsigned)u) << 16;
    return __builtin_bit_cast(float, v);
}

// ---------------- Kernel 1: QKV projection (fp32 GEMM, bf16 out) ----------------
// (round-4/6/7 proven version, verbatim)
// Q  -> natural [bh][n][32], PRE-SCALED by SL = (1/sqrt(128))*log2(e)
// KF -> fragment-ready: KF[((bh*64+t)*4+ct)*512 + l*8 + i] = K[bh][64t+(l&15)+16ct][(l>>4)*8+i]
// VF -> fragment-ready, kv LINEAR: VF[(((bh*64+t)*2+kk)*2+dt)*512 + l*8 + i]
//       = V[bh][64t+kv][(l&15)+16dt], kv = kk*32 + (l>>4)*8 + i
__global__ __launch_bounds__(256) void qkv_kernel(
    const float* __restrict__ x, const float* __restrict__ Wq,
    const float* __restrict__ bq, unsigned short* __restrict__ Qo,
    unsigned short* __restrict__ KFo, unsigned short* __restrict__ VFo)
{
    __shared__ __align__(16) float xT[128][36];   // [k][row]
    const int tid = threadIdx.x;
    const long r0 = (long)blockIdx.x * 32;
    const float SL = (float)(0.08838834764831845 * 1.4426950408889634);
    #pragma unroll
    for (int i = 0; i < 4; ++i) {
        int idx = i * 256 + tid;                   // 1024 float4 tiles
        int row = idx >> 5, kc = (idx & 31) * 4;
        f32x4 v = *(const f32x4*)&x[(r0 + row) * 128 + kc];
        xT[kc + 0][row] = v[0]; xT[kc + 1][row] = v[1];
        xT[kc + 2][row] = v[2]; xT[kc + 3][row] = v[3];
    }
    __syncthreads();
    const int r8 = (tid >> 6) * 8;    // 8-row group
    const int c6 = (tid & 63) * 6;    // 6 consecutive cols
    float acc[6][8];
    #pragma unroll
    for (int j = 0; j < 6; ++j)
        #pragma unroll
        for (int r = 0; r < 8; ++r) acc[j][r] = 0.f;

    for (int k = 0; k < 128; ++k) {
        f32x4 a0 = *(const f32x4*)&xT[k][r8];      // wave-uniform broadcast
        f32x4 a1 = *(const f32x4*)&xT[k][r8 + 4];
        float xr[8] = {a0[0],a0[1],a0[2],a0[3],a1[0],a1[1],a1[2],a1[3]};
        float wv[6];
        #pragma unroll
        for (int u = 0; u < 3; ++u) {
            f32x2 wp = *(const f32x2*)&Wq[k * 384 + c6 + 2 * u];
            wv[2*u] = wp[0]; wv[2*u+1] = wp[1];
        }
        #pragma unroll
        for (int j = 0; j < 6; ++j)
            #pragma unroll
            for (int r = 0; r < 8; ++r) acc[j][r] = fmaf(xr[r], wv[j], acc[j][r]);
    }
    #pragma unroll
    for (int j = 0; j < 6; ++j) {
        int col = c6 + j;
        int h = col / 96, rem = col % 96;
        int d = rem / 3, s = rem % 3;
        float bias = bq[col];
        #pragma unroll
        for (int r = 0; r < 8; ++r) {
            long n = r0 + r8 + r;
            int bb = (int)(n >> 12), nn = (int)(n & 4095);
            int bh = bb * 4 + h;
            int t = nn >> 6, kvi = nn & 63;
            float val = acc[j][r] + bias;
            if (s == 0) {
                unsigned short bits = __builtin_bit_cast(unsigned short, (__bf16)(val * SL));
                Qo[((long)bh * 4096 + nn) * 32 + d] = bits;
            } else if (s == 1) {
                unsigned short bits = __builtin_bit_cast(unsigned short, (__bf16)val);
                int ct = kvi >> 4, lo16 = kvi & 15;
                int gg = d >> 3, ii = d & 7;
                int l = gg * 16 + lo16;
                KFo[(long)(((bh * 64 + t) * 4 + ct) * 512) + l * 8 + ii] = bits;
            } else {
                unsigned short bits = __builtin_bit_cast(unsigned short, (__bf16)val);
                int kk = kvi >> 5, lg = (kvi >> 3) & 3, ii = kvi & 7;
                int l = lg * 16 + (d & 15);
                int dt = d >> 4;
                VFo[(long)((((bh * 64 + t) * 2 + kk) * 2 + dt) * 512) + l * 8 + ii] = bits;
            }
        }
    }
}

// ---------------- Kernel 2: flash attention, 32 q-rows/wave + kv-split x2 ----------------
// Identical numerics to round-7 passing kernel. Scheduling changes only:
// (a) per-BODY sched_barrier(0) removed (P is double-buffered; same-buffer
//     write->read ordering is preserved by alias analysis + in-order DS HW),
// (b) s_setprio(1/0) around the MFMA clusters.
#define MFMA16 __builtin_amdgcn_mfma_f32_16x16x32_bf16

__global__ __launch_bounds__(256, 4) void attn_kernel(
    const unsigned short* __restrict__ Q, const unsigned short* __restrict__ KF,
    const unsigned short* __restrict__ VF, unsigned short* __restrict__ AO)
{
    __shared__ __align__(16) unsigned short P_lds[4][2][2048]; // per-wave dbuf P (32x64)

    const int tid = threadIdx.x, lane = tid & 63, w = tid >> 6;
    const int g = lane >> 4, lo = lane & 15;
    const int wq = w & 1, wh = w >> 1;

    // bijective XCD swizzle over 1024 blocks: each XCD owns 2 consecutive bh
    const int bid = blockIdx.x;
    const int vid = (bid & 7) * 128 + (bid >> 3);
    const int qi = vid & 63, bh = vid >> 6;
    const int q0 = qi * 64 + wq * 32;

    bf16x8 qf[2];
    #pragma unroll
    for (int rt = 0; rt < 2; ++rt) {
        const unsigned short* p = Q + ((long)bh * 4096 + q0 + rt * 16 + lo) * 32 + g * 8;
        qf[rt] = __builtin_bit_cast(bf16x8, *(const u16x8*)p);
    }
    bf16x8 onesf;
    {
        u16x8 ou = {0x3F80,0x3F80,0x3F80,0x3F80,0x3F80,0x3F80,0x3F80,0x3F80};
        onesf = __builtin_bit_cast(bf16x8, ou);
    }
    const f32x4 zf = {0.f, 0.f, 0.f, 0.f};
    f32x4 o_[2][2] = {{zf, zf}, {zf, zf}};
    f32x4 ls[2]    = {zf, zf};

    // P LDS layout: P[q][kv] at short-offset q*64 + (((kv>>3) ^ (q&7))*8) + (kv&7)
    // Swapped QK^T D-layout: s_[rt][ct][j] = S[q = 16rt + lo][kv = 16ct + 4g + j]
    int woff[2][4], roff[2][2];
    #pragma unroll
    for (int qt = 0; qt < 2; ++qt) {
        int q = lo + 16 * qt;
        #pragma unroll
        for (int ct = 0; ct < 4; ++ct) {
            int kvb = 16 * ct + 4 * g;
            woff[qt][ct] = q * 64 + (((kvb >> 3) ^ (q & 7)) * 8) + ((kvb >> 2) & 1) * 4;
        }
    }
    #pragma unroll
    for (int rt = 0; rt < 2; ++rt) {
        int q = lo + 16 * rt;
        #pragma unroll
        for (int kk = 0; kk < 2; ++kk)
            roff[rt][kk] = q * 64 + ((((4 * kk) + g) ^ (q & 7)) * 8);
    }
    unsigned short* B0 = &P_lds[w][0][0];
    unsigned short* B1 = &P_lds[w][1][0];

    const u16x8* kp = (const u16x8*)KF + ((long)bh * 64 + wh * 32) * 256 + lane;
    const u16x8* vp = (const u16x8*)VF + ((long)bh * 64 + wh * 32) * 256 + lane;

    u16x8 K0[4], K1[4], V0[4], V1[4];
    #pragma unroll
    for (int i = 0; i < 4; ++i) K0[i] = kp[i * 64];   // K(first tile of half)
    kp += 256;

// iteration t: prefetch K(t+1)->KN, V(t)->VC; read P(t-1) from BR; QK(t) with KC;
// PV(t-1) with VP; softmax(t) -> BW.
#define BODY(KC, KN, VP, VC, BW, BR, DOPV) do {                                \
    _Pragma("unroll")                                                          \
    for (int i = 0; i < 4; ++i) KN[i] = kp[i * 64];                            \
    kp += 256;                                                                 \
    _Pragma("unroll")                                                          \
    for (int i = 0; i < 4; ++i) VC[i] = vp[i * 64];                            \
    vp += 256;                                                                 \
    u16x8 pa_[2][2];                                                           \
    if (DOPV) {                                                                \
        _Pragma("unroll")                                                      \
        for (int kk = 0; kk < 2; ++kk)                                         \
            _Pragma("unroll")                                                  \
            for (int rt = 0; rt < 2; ++rt)                                     \
                pa_[kk][rt] = *(const u16x8*)&BR[roff[rt][kk]];                \
    }                                                                          \
    f32x4 s_[2][4];                                                            \
    __builtin_amdgcn_s_setprio(1);                                             \
    _Pragma("unroll")                                                          \
    for (int ct = 0; ct < 4; ++ct) {                                           \
        bf16x8 kfr = __builtin_bit_cast(bf16x8, KC[ct]);                       \
        s_[0][ct] = MFMA16(kfr, qf[0], zf, 0, 0, 0);                           \
        s_[1][ct] = MFMA16(kfr, qf[1], zf, 0, 0, 0);                           \
    }                                                                          \
    __builtin_amdgcn_s_setprio(0);                                             \
    if (DOPV) {                                                                \
        __builtin_amdgcn_s_setprio(1);                                         \
        _Pragma("unroll")                                                      \
        for (int kk = 0; kk < 2; ++kk)                                         \
            _Pragma("unroll")                                                  \
            for (int rt = 0; rt < 2; ++rt) {                                   \
                bf16x8 paf = __builtin_bit_cast(bf16x8, pa_[kk][rt]);          \
                ls[rt] = MFMA16(paf, onesf, ls[rt], 0, 0, 0);                  \
                o_[rt][0] = MFMA16(paf, __builtin_bit_cast(bf16x8, VP[kk*2+0]),\
                                   o_[rt][0], 0, 0, 0);                        \
                o_[rt][1] = MFMA16(paf, __builtin_bit_cast(bf16x8, VP[kk*2+1]),\
                                   o_[rt][1], 0, 0, 0);                        \
            }                                                                  \
        __builtin_amdgcn_s_setprio(0);                                         \
    }                                                                          \
    _Pragma("unroll")                                                          \
    for (int qt = 0; qt < 2; ++qt)                                             \
        _Pragma("unroll")                                                      \
        for (int ct = 0; ct < 4; ++ct) {                                       \
            unsigned b0 = __builtin_bit_cast(unsigned,                         \
                __builtin_amdgcn_exp2f(s_[qt][ct][0])) + 0x8000u;              \
            unsigned b1 = __builtin_bit_cast(unsigned,                         \
                __builtin_amdgcn_exp2f(s_[qt][ct][1])) + 0x8000u;              \
            unsigned b2 = __builtin_bit_cast(unsigned,                         \
                __builtin_amdgcn_exp2f(s_[qt][ct][2])) + 0x8000u;              \
            unsigned b3 = __builtin_bit_cast(unsigned,                         \
                __builtin_amdgcn_exp2f(s_[qt][ct][3])) + 0x8000u;              \
            u32x2 wv_;                                                         \
            wv_[0] = __builtin_amdgcn_perm(b1, b0, 0x07060302u);               \
            wv_[1] = __builtin_amdgcn_perm(b3, b2, 0x07060302u);               \
            *(u16x4*)&BW[woff[qt][ct]] = __builtin_bit_cast(u16x4, wv_);       \
        }                                                                      \
} while (0)

    BODY(K0, K1, V1, V0, B0, B1, 0);            // t = 0 of this half (no PV yet)
    #pragma unroll 1
    for (int t = 1; t < 31; t += 2) {
        BODY(K1, K0, V0, V1, B1, B0, 1);        // odd t
        BODY(K0, K1, V1, V0, B0, B1, 1);        // even t+1
    }
    BODY(K1, K0, V0, V1, B1, B0, 1);            // t = 31 (prefetch overshoots: in-bounds ws, unused)
#undef BODY

    // final PV(last): P in B1, V in V1
    #pragma unroll
    for (int kk = 0; kk < 2; ++kk)
        #pragma unroll
        for (int rt = 0; rt < 2; ++rt) {
            bf16x8 paf = __builtin_bit_cast(bf16x8, *(const u16x8*)&B1[roff[rt][kk]]);
            ls[rt] = MFMA16(paf, onesf, ls[rt], 0, 0, 0);
            o_[rt][0] = MFMA16(paf, __builtin_bit_cast(bf16x8, V1[kk*2+0]), o_[rt][0], 0, 0, 0);
            o_[rt][1] = MFMA16(paf, __builtin_bit_cast(bf16x8, V1[kk*2+1]), o_[rt][1], 0, 0, 0);
        }

    // ---- combine kv-halves (partials additive: no-max softmax) ----
    __syncthreads();                      // all P_lds reads done before reuse as scratch
    float* sc = (float*)&P_lds[0][0][0];  // 2 pairs x 64 lanes x 24 f32 = 12 KB
    float* myp = sc + (wq * 64 + lane) * 24;
    if (wh == 1) {
        #pragma unroll
        for (int rt = 0; rt < 2; ++rt)
            #pragma unroll
            for (int dt = 0; dt < 2; ++dt)
                *(f32x4*)&myp[(rt * 2 + dt) * 4] = o_[rt][dt];
        *(f32x4*)&myp[16] = ls[0];
        *(f32x4*)&myp[20] = ls[1];
    }
    __syncthreads();
    if (wh == 0) {
        #pragma unroll
        for (int rt = 0; rt < 2; ++rt) {
            #pragma unroll
            for (int dt = 0; dt < 2; ++dt)
                o_[rt][dt] += *(const f32x4*)&myp[(rt * 2 + dt) * 4];
            ls[rt] += *(const f32x4*)&myp[16 + rt * 4];
        }
        // epilogue: AO[b][n][h*32+d] bf16
        const int bb = bh >> 2, h = bh & 3;
        #pragma unroll
        for (int rt = 0; rt < 2; ++rt)
            #pragma unroll
            for (int j = 0; j < 4; ++j) {
                float rl = __builtin_amdgcn_rcpf(ls[rt][j]);
                int row = q0 + rt * 16 + 4 * g + j;
                #pragma unroll
                for (int dt = 0; dt < 2; ++dt) {
                    int e = h * 32 + lo + 16 * dt;
                    float val = o_[rt][dt][j] * rl;
                    AO[((long)bb * N_SEQ + row) * 128 + e] =
                        __builtin_bit_cast(unsigned short, (__bf16)val);
                }
            }
    }
}

// ---------------- Kernel 3: output projection (fp32 GEMM + bias) ----------------
__global__ __launch_bounds__(256) void proj_kernel(
    const unsigned short* __restrict__ ain, const float* __restrict__ Wp,
    const float* __restrict__ bp, float* __restrict__ out)
{
    __shared__ __align__(16) float xT[128][36];
    const int tid = threadIdx.x;
    const long r0 = (long)blockIdx.x * 32;
    #pragma unroll
    for (int i = 0; i < 2; ++i) {
        int idx = i * 256 + tid;                 // 512 x u16x8
        int row = idx >> 4, kc = (idx & 15) * 8;
        u16x8 v = *(const u16x8*)&ain[(r0 + row) * 128 + kc];
        #pragma unroll
        for (int e = 0; e < 8; ++e) xT[kc + e][row] = bf2f(v[e]);
    }
    __syncthreads();
    const int r8 = (tid >> 6) * 8;
    const int c  = tid & 63;
    float acc0[8], acc1[8];
    #pragma unroll
    for (int r = 0; r < 8; ++r) { acc0[r] = 0.f; acc1[r] = 0.f; }
    for (int k = 0; k < 128; ++k) {
        f32x4 a0 = *(const f32x4*)&xT[k][r8];
        f32x4 a1 = *(const f32x4*)&xT[k][r8 + 4];
        float xr[8] = {a0[0],a0[1],a0[2],a0[3],a1[0],a1[1],a1[2],a1[3]};
        float w0 = Wp[k * 128 + c];
        float w1 = Wp[k * 128 + c + 64];
        #pragma unroll
        for (int r = 0; r < 8; ++r) {
            acc0[r] = fmaf(xr[r], w0, acc0[r]);
            acc1[r] = fmaf(xr[r], w1, acc1[r]);
        }
    }
    float b0 = bp[c], b1 = bp[c + 64];
    #pragma unroll
    for (int r = 0; r < 8; ++r) {
        long n = r0 + r8 + r;
        out[n * 128 + c]      = acc0[r] + b0;
        out[n * 128 + c + 64] = acc1[r] + b1;
    }
}

extern "C" void kernel_launch(void* const* d_in, const int* in_sizes, int n_in,
                              void* d_out, int out_size, void* d_ws, size_t ws_size,
                              hipStream_t stream)
{
    const float* x  = (const float*)d_in[0];
    const float* Wq = (const float*)d_in[1];
    const float* bq = (const float*)d_in[2];
    const float* Wp = (const float*)d_in[3];
    const float* bp = (const float*)d_in[4];
    float* out = (float*)d_out;

    // workspace: Q (4MB) | KF (4MB) | VF (4MB) | attn-out (4MB), all bf16
    unsigned short* Qw  = (unsigned short*)d_ws;
    unsigned short* KFw = Qw  + (size_t)16 * 4096 * 32;
    unsigned short* VFw = KFw + (size_t)16 * 4096 * 32;
    unsigned short* AOw = VFw + (size_t)16 * 4096 * 32;

    qkv_kernel<<<512, 256, 0, stream>>>(x, Wq, bq, Qw, KFw, VFw);
    attn_kernel<<<1024, 256, 0, stream>>>(Qw, KFw, VFw, AOw);
    proj_kernel<<<512, 256, 0, stream>>>(AOw, Wp, bp, out);
}

// Round 9
// 93.223 us; speedup vs baseline: 2.1005x; 2.1005x over previous
//
#include <hip/hip_runtime.h>
#include <stdint.h>

#define N_SEQ 4096
#define MFMA16 __builtin_amdgcn_mfma_f32_16x16x32_bf16

typedef float f32x4 __attribute__((ext_vector_type(4)));
typedef float f32x2 __attribute__((ext_vector_type(2)));
typedef unsigned short u16x8 __attribute__((ext_vector_type(8)));
typedef unsigned short u16x4 __attribute__((ext_vector_type(4)));
typedef unsigned int u32x2 __attribute__((ext_vector_type(2)));
typedef __bf16 bf16x8 __attribute__((ext_vector_type(8)));

static __device__ __forceinline__ float bf2f(unsigned short u) {
    unsigned v = ((unsigned)u) << 16;
    return __builtin_bit_cast(float, v);
}

// ---------------- Kernel 0: repack W_qkv -> bf16 fragment-ready ----------------
// WqF[(ct*4+ks)*512 + l*8 + i] = Wq[ks*32 + (l>>4)*8 + i][ct*16 + (l&15)], ct in [0,24)
__global__ __launch_bounds__(256) void wrepack_kernel(
    const float* __restrict__ Wq, unsigned short* __restrict__ WqF)
{
    int idx = blockIdx.x * 256 + threadIdx.x;   // [0, 49152)
    int i = idx & 7, l = (idx >> 3) & 63, fr = idx >> 9;
    int ct = fr >> 2, ks = fr & 3;
    int k = ks * 32 + (l >> 4) * 8 + i;
    int col = ct * 16 + (l & 15);
    WqF[idx] = __builtin_bit_cast(unsigned short, (__bf16)Wq[k * 384 + col]);
}

// ---------------- Kernel 1: QKV projection via MFMA (bf16 in/out, fp32 acc) ----------------
// Block = 32 tokens x 384 cols; wave w owns head h = w (cols w*96..w*96+95).
// D-layout (verified in attn): lane l, reg j of acc[rt][c] = C[token r0+rt*16+4g+j][col (w*6+c)*16+lo].
// Output layouts identical to the round-4/6/7 proven kernel:
// Q[bh][n][32] (pre-scaled by SL); KF/VF fragment-ready (see formulas in round-7 source).
__global__ __launch_bounds__(256) void qkv_kernel(
    const float* __restrict__ x, const unsigned short* __restrict__ WqF,
    const float* __restrict__ bq, unsigned short* __restrict__ Qo,
    unsigned short* __restrict__ KFo, unsigned short* __restrict__ VFo)
{
    const int tid = threadIdx.x, lane = tid & 63, w = tid >> 6;
    const int g = lane >> 4, lo = lane & 15;
    const long r0 = (long)blockIdx.x * 32;
    const float SL = (float)(0.08838834764831845 * 1.4426950408889634);
    const f32x4 zf = {0.f, 0.f, 0.f, 0.f};

    // A-fragments of x (bf16 cvt in-register): xf[rt][ks], k = ks*32 + g*8 + i
    bf16x8 xf[2][4];
    #pragma unroll
    for (int rt = 0; rt < 2; ++rt) {
        const float* xr = x + (r0 + rt * 16 + lo) * 128 + g * 8;
        #pragma unroll
        for (int ks = 0; ks < 4; ++ks) {
            f32x4 a = *(const f32x4*)&xr[ks * 32];
            f32x4 b = *(const f32x4*)&xr[ks * 32 + 4];
            bf16x8 f;
            f[0] = (__bf16)a[0]; f[1] = (__bf16)a[1]; f[2] = (__bf16)a[2]; f[3] = (__bf16)a[3];
            f[4] = (__bf16)b[0]; f[5] = (__bf16)b[1]; f[6] = (__bf16)b[2]; f[7] = (__bf16)b[3];
            xf[rt][ks] = f;
        }
    }
    f32x4 acc[2][6];
    #pragma unroll
    for (int rt = 0; rt < 2; ++rt)
        #pragma unroll
        for (int c = 0; c < 6; ++c) acc[rt][c] = zf;

    const u16x8* wp = (const u16x8*)WqF + (size_t)(w * 24) * 64 + lane;
    #pragma unroll
    for (int c = 0; c < 6; ++c)
        #pragma unroll
        for (int ks = 0; ks < 4; ++ks) {
            bf16x8 wf = __builtin_bit_cast(bf16x8, wp[(c * 4 + ks) * 64]);
            acc[0][c] = MFMA16(xf[0][ks], wf, acc[0][c], 0, 0, 0);
            acc[1][c] = MFMA16(xf[1][ks], wf, acc[1][c], 0, 0, 0);
        }

    // epilogue: per lane, col fixed per c-tile -> fixed (h=w, d, s); rows vary with j.
    const int bb = (int)(r0 >> 12), nn0 = (int)(r0 & 4095);
    const int bh = bb * 4 + w;
    const int t = nn0 >> 6, kvb = nn0 & 63;   // kvb in {0,32}
    const int kk = kvb >> 5;
    #pragma unroll
    for (int c = 0; c < 6; ++c) {
        int col = (w * 6 + c) * 16 + lo;
        int rem = col - w * 96;              // col % 96
        int d = rem / 3, s = rem % 3;
        float bias = bq[col];
        #pragma unroll
        for (int rt = 0; rt < 2; ++rt) {
            float scale = (s == 0) ? SL : 1.0f;
            unsigned short bits[4];
            #pragma unroll
            for (int j = 0; j < 4; ++j)
                bits[j] = __builtin_bit_cast(unsigned short,
                              (__bf16)((acc[rt][c][j] + bias) * scale));
            if (s == 0) {
                long base = ((long)bh * 4096 + nn0 + rt * 16 + 4 * g) * 32 + d;
                #pragma unroll
                for (int j = 0; j < 4; ++j) Qo[base + (long)j * 32] = bits[j];
            } else if (s == 1) {
                int ct_k = (kvb >> 4) + rt;   // kvi>>4 ; kvi&15 = 4g+j
                long base = (long)((bh * 64 + t) * 4 + ct_k) * 512
                          + ((d >> 3) * 16 + 4 * g) * 8 + (d & 7);
                #pragma unroll
                for (int j = 0; j < 4; ++j) KFo[base + j * 8] = bits[j];
            } else {
                int lg = rt * 2 + (g >> 1);   // (kvi>>3)&3 ; i = (4g&7)+j consecutive
                long base = (long)(((bh * 64 + t) * 2 + kk) * 2 + (d >> 4)) * 512
                          + (lg * 16 + (d & 15)) * 8 + ((4 * g) & 7);
                u16x4 pk = {bits[0], bits[1], bits[2], bits[3]};
                *(u16x4*)&VFo[base] = pk;
            }
        }
    }
}

// ---------------- Kernel 2: flash attention (round-7 proven version, verbatim) ----------------
__global__ __launch_bounds__(256, 4) void attn_kernel(
    const unsigned short* __restrict__ Q, const unsigned short* __restrict__ KF,
    const unsigned short* __restrict__ VF, unsigned short* __restrict__ AO)
{
    __shared__ __align__(16) unsigned short P_lds[4][2][2048]; // per-wave dbuf P (32x64)

    const int tid = threadIdx.x, lane = tid & 63, w = tid >> 6;
    const int g = lane >> 4, lo = lane & 15;
    const int wq = w & 1, wh = w >> 1;

    const int bid = blockIdx.x;
    const int vid = (bid & 7) * 128 + (bid >> 3);
    const int qi = vid & 63, bh = vid >> 6;
    const int q0 = qi * 64 + wq * 32;

    bf16x8 qf[2];
    #pragma unroll
    for (int rt = 0; rt < 2; ++rt) {
        const unsigned short* p = Q + ((long)bh * 4096 + q0 + rt * 16 + lo) * 32 + g * 8;
        qf[rt] = __builtin_bit_cast(bf16x8, *(const u16x8*)p);
    }
    bf16x8 onesf;
    {
        u16x8 ou = {0x3F80,0x3F80,0x3F80,0x3F80,0x3F80,0x3F80,0x3F80,0x3F80};
        onesf = __builtin_bit_cast(bf16x8, ou);
    }
    const f32x4 zf = {0.f, 0.f, 0.f, 0.f};
    f32x4 o_[2][2] = {{zf, zf}, {zf, zf}};
    f32x4 ls[2]    = {zf, zf};

    int woff[2][4], roff[2][2];
    #pragma unroll
    for (int qt = 0; qt < 2; ++qt) {
        int q = lo + 16 * qt;
        #pragma unroll
        for (int ct = 0; ct < 4; ++ct) {
            int kvb = 16 * ct + 4 * g;
            woff[qt][ct] = q * 64 + (((kvb >> 3) ^ (q & 7)) * 8) + ((kvb >> 2) & 1) * 4;
        }
    }
    #pragma unroll
    for (int rt = 0; rt < 2; ++rt) {
        int q = lo + 16 * rt;
        #pragma unroll
        for (int kk = 0; kk < 2; ++kk)
            roff[rt][kk] = q * 64 + ((((4 * kk) + g) ^ (q & 7)) * 8);
    }
    unsigned short* B0 = &P_lds[w][0][0];
    unsigned short* B1 = &P_lds[w][1][0];

    const u16x8* kp = (const u16x8*)KF + ((long)bh * 64 + wh * 32) * 256 + lane;
    const u16x8* vp = (const u16x8*)VF + ((long)bh * 64 + wh * 32) * 256 + lane;

    u16x8 K0[4], K1[4], V0[4], V1[4];
    #pragma unroll
    for (int i = 0; i < 4; ++i) K0[i] = kp[i * 64];
    kp += 256;

#define BODY(KC, KN, VP, VC, BW, BR, DOPV) do {                                \
    _Pragma("unroll")                                                          \
    for (int i = 0; i < 4; ++i) KN[i] = kp[i * 64];                            \
    kp += 256;                                                                 \
    _Pragma("unroll")                                                          \
    for (int i = 0; i < 4; ++i) VC[i] = vp[i * 64];                            \
    vp += 256;                                                                 \
    u16x8 pa_[2][2];                                                           \
    if (DOPV) {                                                                \
        _Pragma("unroll")                                                      \
        for (int kk = 0; kk < 2; ++kk)                                         \
            _Pragma("unroll")                                                  \
            for (int rt = 0; rt < 2; ++rt)                                     \
                pa_[kk][rt] = *(const u16x8*)&BR[roff[rt][kk]];                \
    }                                                                          \
    f32x4 s_[2][4];                                                            \
    _Pragma("unroll")                                                          \
    for (int ct = 0; ct < 4; ++ct) {                                           \
        bf16x8 kfr = __builtin_bit_cast(bf16x8, KC[ct]);                       \
        s_[0][ct] = MFMA16(kfr, qf[0], zf, 0, 0, 0);                           \
        s_[1][ct] = MFMA16(kfr, qf[1], zf, 0, 0, 0);                           \
    }                                                                          \
    if (DOPV) {                                                                \
        _Pragma("unroll")                                                      \
        for (int kk = 0; kk < 2; ++kk)                                         \
            _Pragma("unroll")                                                  \
            for (int rt = 0; rt < 2; ++rt) {                                   \
                bf16x8 paf = __builtin_bit_cast(bf16x8, pa_[kk][rt]);          \
                ls[rt] = MFMA16(paf, onesf, ls[rt], 0, 0, 0);                  \
                o_[rt][0] = MFMA16(paf, __builtin_bit_cast(bf16x8, VP[kk*2+0]),\
                                   o_[rt][0], 0, 0, 0);                        \
                o_[rt][1] = MFMA16(paf, __builtin_bit_cast(bf16x8, VP[kk*2+1]),\
                                   o_[rt][1], 0, 0, 0);                        \
            }                                                                  \
    }                                                                          \
    _Pragma("unroll")                                                          \
    for (int qt = 0; qt < 2; ++qt)                                             \
        _Pragma("unroll")                                                      \
        for (int ct = 0; ct < 4; ++ct) {                                       \
            unsigned b0 = __builtin_bit_cast(unsigned,                         \
                __builtin_amdgcn_exp2f(s_[qt][ct][0])) + 0x8000u;              \
            unsigned b1 = __builtin_bit_cast(unsigned,                         \
                __builtin_amdgcn_exp2f(s_[qt][ct][1])) + 0x8000u;              \
            unsigned b2 = __builtin_bit_cast(unsigned,                         \
                __builtin_amdgcn_exp2f(s_[qt][ct][2])) + 0x8000u;              \
            unsigned b3 = __builtin_bit_cast(unsigned,                         \
                __builtin_amdgcn_exp2f(s_[qt][ct][3])) + 0x8000u;              \
            u32x2 wv_;                                                         \
            wv_[0] = __builtin_amdgcn_perm(b1, b0, 0x07060302u);               \
            wv_[1] = __builtin_amdgcn_perm(b3, b2, 0x07060302u);               \
            *(u16x4*)&BW[woff[qt][ct]] = __builtin_bit_cast(u16x4, wv_);       \
        }                                                                      \
    __builtin_amdgcn_sched_barrier(0);                                         \
} while (0)

    BODY(K0, K1, V1, V0, B0, B1, 0);
    #pragma unroll 1
    for (int t = 1; t < 31; t += 2) {
        BODY(K1, K0, V0, V1, B1, B0, 1);
        BODY(K0, K1, V1, V0, B0, B1, 1);
    }
    BODY(K1, K0, V0, V1, B1, B0, 1);
#undef BODY

    #pragma unroll
    for (int kk = 0; kk < 2; ++kk)
        #pragma unroll
        for (int rt = 0; rt < 2; ++rt) {
            bf16x8 paf = __builtin_bit_cast(bf16x8, *(const u16x8*)&B1[roff[rt][kk]]);
            ls[rt] = MFMA16(paf, onesf, ls[rt], 0, 0, 0);
            o_[rt][0] = MFMA16(paf, __builtin_bit_cast(bf16x8, V1[kk*2+0]), o_[rt][0], 0, 0, 0);
            o_[rt][1] = MFMA16(paf, __builtin_bit_cast(bf16x8, V1[kk*2+1]), o_[rt][1], 0, 0, 0);
        }

    __syncthreads();
    float* sc = (float*)&P_lds[0][0][0];
    float* myp = sc + (wq * 64 + lane) * 24;
    if (wh == 1) {
        #pragma unroll
        for (int rt = 0; rt < 2; ++rt)
            #pragma unroll
            for (int dt = 0; dt < 2; ++dt)
                *(f32x4*)&myp[(rt * 2 + dt) * 4] = o_[rt][dt];
        *(f32x4*)&myp[16] = ls[0];
        *(f32x4*)&myp[20] = ls[1];
    }
    __syncthreads();
    if (wh == 0) {
        #pragma unroll
        for (int rt = 0; rt < 2; ++rt) {
            #pragma unroll
            for (int dt = 0; dt < 2; ++dt)
                o_[rt][dt] += *(const f32x4*)&myp[(rt * 2 + dt) * 4];
            ls[rt] += *(const f32x4*)&myp[16 + rt * 4];
        }
        const int bb = bh >> 2, h = bh & 3;
        #pragma unroll
        for (int rt = 0; rt < 2; ++rt)
            #pragma unroll
            for (int j = 0; j < 4; ++j) {
                float rl = __builtin_amdgcn_rcpf(ls[rt][j]);
                int row = q0 + rt * 16 + 4 * g + j;
                #pragma unroll
                for (int dt = 0; dt < 2; ++dt) {
                    int e = h * 32 + lo + 16 * dt;
                    float val = o_[rt][dt][j] * rl;
                    AO[((long)bb * N_SEQ + row) * 128 + e] =
                        __builtin_bit_cast(unsigned short, (__bf16)val);
                }
            }
    }
}

// ---------------- Kernel 3: output projection (fp32 GEMM + bias, proven) ----------------
__global__ __launch_bounds__(256) void proj_kernel(
    const unsigned short* __restrict__ ain, const float* __restrict__ Wp,
    const float* __restrict__ bp, float* __restrict__ out)
{
    __shared__ __align__(16) float xT[128][36];
    const int tid = threadIdx.x;
    const long r0 = (long)blockIdx.x * 32;
    #pragma unroll
    for (int i = 0; i < 2; ++i) {
        int idx = i * 256 + tid;
        int row = idx >> 4, kc = (idx & 15) * 8;
        u16x8 v = *(const u16x8*)&ain[(r0 + row) * 128 + kc];
        #pragma unroll
        for (int e = 0; e < 8; ++e) xT[kc + e][row] = bf2f(v[e]);
    }
    __syncthreads();
    const int r8 = (tid >> 6) * 8;
    const int c  = tid & 63;
    float acc0[8], acc1[8];
    #pragma unroll
    for (int r = 0; r < 8; ++r) { acc0[r] = 0.f; acc1[r] = 0.f; }
    for (int k = 0; k < 128; ++k) {
        f32x4 a0 = *(const f32x4*)&xT[k][r8];
        f32x4 a1 = *(const f32x4*)&xT[k][r8 + 4];
        float xr[8] = {a0[0],a0[1],a0[2],a0[3],a1[0],a1[1],a1[2],a1[3]};
        float w0 = Wp[k * 128 + c];
        float w1 = Wp[k * 128 + c + 64];
        #pragma unroll
        for (int r = 0; r < 8; ++r) {
            acc0[r] = fmaf(xr[r], w0, acc0[r]);
            acc1[r] = fmaf(xr[r], w1, acc1[r]);
        }
    }
    float b0 = bp[c], b1 = bp[c + 64];
    #pragma unroll
    for (int r = 0; r < 8; ++r) {
        long n = r0 + r8 + r;
        out[n * 128 + c]      = acc0[r] + b0;
        out[n * 128 + c + 64] = acc1[r] + b1;
    }
}

extern "C" void kernel_launch(void* const* d_in, const int* in_sizes, int n_in,
                              void* d_out, int out_size, void* d_ws, size_t ws_size,
                              hipStream_t stream)
{
    const float* x  = (const float*)d_in[0];
    const float* Wq = (const float*)d_in[1];
    const float* bq = (const float*)d_in[2];
    const float* Wp = (const float*)d_in[3];
    const float* bp = (const float*)d_in[4];
    float* out = (float*)d_out;

    // workspace: Q (4MB) | KF (4MB) | VF (4MB) | attn-out (4MB) | WqF (96KB), all bf16
    unsigned short* Qw   = (unsigned short*)d_ws;
    unsigned short* KFw  = Qw  + (size_t)16 * 4096 * 32;
    unsigned short* VFw  = KFw + (size_t)16 * 4096 * 32;
    unsigned short* AOw  = VFw + (size_t)16 * 4096 * 32;
    unsigned short* WqFw = AOw + (size_t)16 * 4096 * 32;

    wrepack_kernel<<<192, 256, 0, stream>>>(Wq, WqFw);
    qkv_kernel<<<512, 256, 0, stream>>>(x, WqFw, bq, Qw, KFw, VFw);
    attn_kernel<<<1024, 256, 0, stream>>>(Qw, KFw, VFw, AOw);
    proj_kernel<<<512, 256, 0, stream>>>(AOw, Wp, bp, out);
}